// Round 6
// baseline (124.181 us; speedup 1.0000x reference)
//
#include <hip/hip_runtime.h>
#include <hip/hip_bf16.h>
#include <math.h>

// vec[b,e] = sum_s softmax_s( tanh(theta@w.T [b,:] + h[b,s,:]@u) @ v ) * h[b,s,e]
// B=64, S=2048, E=256, T=100
// R6: persistent blocks (4 chunks each, grid 512 = 2 blocks/CU exactly),
//     double-buffered LDS h tile, stage of chunk c+1 interleaved in quarters
//     with the MFMA K-loop of chunk c (T14 issue-early/write-late).

#define E_DIM 256
#define GM 64        // s-rows per chunk
#define NC 4         // chunks per block

typedef __bf16 bf16x8 __attribute__((ext_vector_type(8)));
typedef float  f32x4  __attribute__((ext_vector_type(4)));

__device__ __forceinline__ unsigned short f2bf(float x) {
    return __builtin_bit_cast(unsigned short, (__bf16)x);
}
__device__ __forceinline__ float bf2f(unsigned short b) {
    return __builtin_bit_cast(float, (unsigned)b << 16);
}

// XOR-swizzle for a [64][256] bf16 tile (512 B rows): spread 16B-slot index by row&7.
// Only touches byte bits 4-6; tile-base offsets (>=32KB) are unaffected.
__device__ __forceinline__ unsigned swz(unsigned byte) {
    return byte ^ ((((byte) >> 9) & 7) << 4);
}

// tanh(x) = 1 - 2/(exp(2x)+1); overflow-safe (rcp(inf)=0).
__device__ __forceinline__ float fast_tanh(float x) {
    const float e = __expf(2.0f * x);
    const float r = __builtin_amdgcn_rcpf(e + 1.0f);
    return fmaf(-2.0f, r, 1.0f);
}

// ---------------- Kernel 0: u_t[f][e] = bf16(u[e][f]) ----------------
__global__ __launch_bounds__(256) void k_transpose(const float* __restrict__ u,
                                                   unsigned short* __restrict__ u_t) {
    const int f = blockIdx.x, e = threadIdx.x;
    u_t[(size_t)f * E_DIM + e] = f2bf(u[(size_t)e * E_DIM + f]);
}

// ---------------- Kernel 1: tw[b,e] = sum_t theta[b,t] * w[e,t] ----------------
__global__ __launch_bounds__(E_DIM) void k_thetaw(const float* __restrict__ theta,
                                                  const float* __restrict__ w,
                                                  float* __restrict__ tw,
                                                  int T) {
    __shared__ float th[128];
    const int b = blockIdx.x;
    const int e = threadIdx.x;
    if (threadIdx.x < T) th[threadIdx.x] = theta[b * T + threadIdx.x];
    __syncthreads();
    float acc = 0.f;
    for (int t = 0; t < T; ++t) acc = fmaf(th[t], w[e * T + t], acc);
    tw[b * E_DIM + e] = acc;
}

// ---------------- Kernel 2 (fused, persistent over NC chunks) ----------------
__global__ __launch_bounds__(256, 2) void k_gate_fused(const float* __restrict__ h,
                                                       const unsigned short* __restrict__ u_t,
                                                       const float* __restrict__ tw_,
                                                       const float* __restrict__ v,
                                                       float* __restrict__ partial,
                                                       float* __restrict__ pm,
                                                       float* __restrict__ pd,
                                                       int S, int SC) {
    __shared__ unsigned short h_lds[2][GM * E_DIM];  // 2 x 32 KB, swizzled
    __shared__ float red[4][GM];                     // 1 KB
    __shared__ float exw[GM];                        // 256 B
    __shared__ float pacc[4][E_DIM];                 // 4 KB

    const int b   = blockIdx.y;
    const int sc0 = blockIdx.x * NC;
    const int tid = threadIdx.x;
    const int w   = tid >> 6;      // wave 0..3
    const int l   = tid & 63;      // lane
    const int lg  = l >> 4;        // k-group 0..3
    const int lc  = l & 15;        // row/col class 0..15
    const int f0w = w * 64;        // wave's f-range base

    // ---- preload ENTIRE per-wave u-slice into registers (32 x bf16x8 = 128 VGPR) ----
    bf16x8 ub[8][4];   // [kt][n]
#pragma unroll
    for (int kt = 0; kt < 8; ++kt)
#pragma unroll
        for (int n = 0; n < 4; ++n)
            ub[kt][n] = *reinterpret_cast<const bf16x8*>(
                u_t + (size_t)(f0w + n * 16 + lc) * E_DIM + kt * 32 + lg * 8);

    // ---- prologue: stage chunk sc0 into buffer 0 (overlaps with ub loads) ----
    {
        const float* hb = h + ((size_t)b * S + sc0 * GM) * E_DIM;
        char* ldsb = (char*)h_lds[0];
        float4 st[16];
#pragma unroll
        for (int it = 0; it < 16; ++it)
            st[it] = *reinterpret_cast<const float4*>(hb + (size_t)(it * 4 + w) * E_DIM + l * 4);
#pragma unroll
        for (int it = 0; it < 16; ++it) {
            uint2 pk;
            pk.x = (unsigned)f2bf(st[it].x) | ((unsigned)f2bf(st[it].y) << 16);
            pk.y = (unsigned)f2bf(st[it].z) | ((unsigned)f2bf(st[it].w) << 16);
            *reinterpret_cast<uint2*>(ldsb + swz((it * 4 + w) * 512 + l * 8)) = pk;
        }
    }

    // ---- per-wave epilogue constants ----
    float tw_f[4], v_f[4];
#pragma unroll
    for (int n = 0; n < 4; ++n) {
        const int f = f0w + n * 16 + lc;
        tw_f[n] = tw_[b * E_DIM + f];
        v_f[n]  = v[f];
    }

    __syncthreads();   // tile 0 ready

    for (int c = 0; c < NC; ++c) {
        const int sc = sc0 + c;
        char* cur = (char*)h_lds[c & 1];
        char* nxt = (char*)h_lds[(c & 1) ^ 1];
        const float* hbn = h + ((size_t)b * S + (sc + 1) * GM) * E_DIM;
        const bool prefetch = (c < NC - 1);

        f32x4 acc[4][4];
#pragma unroll
        for (int m = 0; m < 4; ++m)
#pragma unroll
            for (int n = 0; n < 4; ++n)
                acc[m][n] = (f32x4){0.f, 0.f, 0.f, 0.f};

        // ---- K loop on tile c, interleaved with quarter-staging of tile c+1 ----
#pragma unroll
        for (int q = 0; q < 4; ++q) {
            float4 st[4];
            if (prefetch) {
#pragma unroll
                for (int j = 0; j < 4; ++j) {
                    const int row = q * 16 + j * 4 + w;
                    st[j] = *reinterpret_cast<const float4*>(hbn + (size_t)row * E_DIM + l * 4);
                }
            }
#pragma unroll
            for (int kk = 0; kk < 2; ++kk) {
                const int kt = q * 2 + kk;
                bf16x8 af[4];
#pragma unroll
                for (int m = 0; m < 4; ++m)
                    af[m] = *reinterpret_cast<const bf16x8*>(
                        cur + swz((m * 16 + lc) * 512 + kt * 64 + lg * 16));
#pragma unroll
                for (int m = 0; m < 4; ++m)
#pragma unroll
                    for (int n = 0; n < 4; ++n)
                        acc[m][n] = __builtin_amdgcn_mfma_f32_16x16x32_bf16(
                            af[m], ub[kt][n], acc[m][n], 0, 0, 0);
            }
            if (prefetch) {
#pragma unroll
                for (int j = 0; j < 4; ++j) {
                    const int row = q * 16 + j * 4 + w;
                    uint2 pk;
                    pk.x = (unsigned)f2bf(st[j].x) | ((unsigned)f2bf(st[j].y) << 16);
                    pk.y = (unsigned)f2bf(st[j].z) | ((unsigned)f2bf(st[j].w) << 16);
                    *reinterpret_cast<uint2*>(nxt + swz(row * 512 + l * 8)) = pk;
                }
            }
        }

        // ---- gate epilogue: tanh(z+tw)*v, sum over f (lc-classes then waves) ----
        float part[4][4] = {};   // [m][i]; row = m*16 + lg*4 + i, col-class lc
#pragma unroll
        for (int n = 0; n < 4; ++n)
#pragma unroll
            for (int m = 0; m < 4; ++m)
#pragma unroll
                for (int i = 0; i < 4; ++i)
                    part[m][i] += fast_tanh(acc[m][n][i] + tw_f[n]) * v_f[n];

#pragma unroll
        for (int off = 1; off < 16; off <<= 1)
#pragma unroll
            for (int m = 0; m < 4; ++m)
#pragma unroll
                for (int i = 0; i < 4; ++i)
                    part[m][i] += __shfl_xor(part[m][i], off, 64);

        if (lc == 0) {
#pragma unroll
            for (int m = 0; m < 4; ++m)
#pragma unroll
                for (int i = 0; i < 4; ++i)
                    red[w][m * 16 + lg * 4 + i] = part[m][i];
        }
        __syncthreads();   // b1: red ready (also: all tile-c+1 ds_writes done)

        // ---- block softmax stats: wave 0 owns the 64 g values ----
        if (tid < GM) {
            const float g = red[0][tid] + red[1][tid] + red[2][tid] + red[3][tid];
            float mx = g;
#pragma unroll
            for (int off = 1; off < 64; off <<= 1)
                mx = fmaxf(mx, __shfl_xor(mx, off, 64));
            const float ex = __expf(g - mx);
            float d = ex;
#pragma unroll
            for (int off = 1; off < 64; off <<= 1)
                d += __shfl_xor(d, off, 64);
            exw[tid] = ex;
            if (tid == 0) {
                pm[(size_t)b * SC + sc] = mx;
                pd[(size_t)b * SC + sc] = d;
            }
        }
        __syncthreads();   // b2: exw ready

        // ---- weighted partial: wave w sums rows w*16..w*16+15; lane owns 4 e-cols ----
        f32x4 a4 = (f32x4){0.f, 0.f, 0.f, 0.f};
#pragma unroll
        for (int j = 0; j < 16; ++j) {
            const int row = w * 16 + j;
            const float ws = exw[row];
            const uint2 hv = *reinterpret_cast<const uint2*>(cur + swz(row * 512 + l * 8));
            a4[0] = fmaf(ws, bf2f((unsigned short)(hv.x & 0xffff)), a4[0]);
            a4[1] = fmaf(ws, bf2f((unsigned short)(hv.x >> 16)),    a4[1]);
            a4[2] = fmaf(ws, bf2f((unsigned short)(hv.y & 0xffff)), a4[2]);
            a4[3] = fmaf(ws, bf2f((unsigned short)(hv.y >> 16)),    a4[3]);
        }
        *reinterpret_cast<f32x4*>(&pacc[w][l * 4]) = a4;
        __syncthreads();   // b3: pacc ready; tile c free for re-staging

        const float p = pacc[0][tid] + pacc[1][tid] + pacc[2][tid] + pacc[3][tid];
        partial[((size_t)b * SC + sc) * E_DIM + tid] = p;
    }
}

// ---------------- Kernel 3: exact softmax merge across chunks ----------------
__global__ __launch_bounds__(256) void k_combine(const float* __restrict__ partial,
                                                 const float* __restrict__ pm,
                                                 const float* __restrict__ pd,
                                                 float* __restrict__ out,
                                                 int SC) {
    const int b = blockIdx.x, t = threadIdx.x;
    __shared__ float sm[64], sd[64];
    if (t < SC) {
        sm[t] = pm[(size_t)b * SC + t];
        sd[t] = pd[(size_t)b * SC + t];
    }
    __syncthreads();

    float M = -3.4e38f;
    for (int c = 0; c < SC; ++c) M = fmaxf(M, sm[c]);

    float num = 0.f, den = 0.f;
    for (int c = 0; c < SC; ++c) {
        const float s = __expf(sm[c] - M);
        den = fmaf(s, sd[c], den);
        num = fmaf(s, partial[((size_t)b * SC + c) * E_DIM + t], num);
    }
    out[(size_t)b * E_DIM + t] = num / den;
}

extern "C" void kernel_launch(void* const* d_in, const int* in_sizes, int n_in,
                              void* d_out, int out_size, void* d_ws, size_t ws_size,
                              hipStream_t stream) {
    const float* h     = (const float*)d_in[0];
    const float* theta = (const float*)d_in[1];
    const float* w     = (const float*)d_in[2];
    const float* v     = (const float*)d_in[3];
    const float* u     = (const float*)d_in[4];
    float* out = (float*)d_out;

    const int E = in_sizes[3];              // 256
    const int T = in_sizes[2] / E;          // 100
    const int B = in_sizes[1] / T;          // 64
    const int S = in_sizes[0] / (B * E);    // 2048
    const int SC = S / GM;                  // 32

    float* tw = (float*)d_ws;                                     // [B,E]
    unsigned short* u_t = (unsigned short*)(tw + (size_t)B * E);  // [E,E] bf16
    float* partial = (float*)(u_t + (size_t)E * E);               // [B,SC,E]
    float* pm = partial + (size_t)B * SC * E;                     // [B,SC]
    float* pd = pm + (size_t)B * SC;                              // [B,SC]

    k_transpose<<<dim3(E), dim3(E), 0, stream>>>(u, u_t);
    k_thetaw<<<dim3(B), dim3(E), 0, stream>>>(theta, w, tw, T);
    k_gate_fused<<<dim3(SC / NC, B), dim3(256), 0, stream>>>(h, u_t, tw, v, partial, pm, pd, S, SC);
    k_combine<<<dim3(B), dim3(256), 0, stream>>>(partial, pm, pd, out, SC);
}

// Round 7
// 88.670 us; speedup vs baseline: 1.4005x; 1.4005x over previous
//
#include <hip/hip_runtime.h>
#include <hip/hip_bf16.h>
#include <math.h>

// vec[b,e] = sum_s softmax_s( tanh(theta@w.T [b,:] + h[b,s,:]@u) @ v ) * h[b,s,e]
// B=64, S=2048, E=256, T=100
// R7: register-budgeted fused kernel. GM=32 (acc 32 regs), 4 blocks/CU
//     (16 waves/CU) for TLP-based overlap; u streamed from L2 via 2-deep
//     register ring inside a NON-unrolled loop (prevents hoist->spill).
//     Peak ~100 VGPR, no spill.

#define E_DIM 256
#define GM 32        // s-rows per block

typedef __bf16 bf16x8 __attribute__((ext_vector_type(8)));
typedef float  f32x4  __attribute__((ext_vector_type(4)));

__device__ __forceinline__ unsigned short f2bf(float x) {
    return __builtin_bit_cast(unsigned short, (__bf16)x);
}
__device__ __forceinline__ float bf2f(unsigned short b) {
    return __builtin_bit_cast(float, (unsigned)b << 16);
}

// XOR-swizzle for 512 B rows: flip 16B-slot bits 4-6 by row&7 (row = byte>>9).
__device__ __forceinline__ unsigned swz(unsigned byte) {
    return byte ^ ((((byte) >> 9) & 7) << 4);
}

// tanh(x) = 1 - 2/(exp(2x)+1); overflow-safe (rcp(inf)=0).
__device__ __forceinline__ float fast_tanh(float x) {
    const float e = __expf(2.0f * x);
    const float r = __builtin_amdgcn_rcpf(e + 1.0f);
    return fmaf(-2.0f, r, 1.0f);
}

// ---------------- Kernel 0: u_t[f][e] = bf16(u[e][f]) ----------------
__global__ __launch_bounds__(256) void k_transpose(const float* __restrict__ u,
                                                   unsigned short* __restrict__ u_t) {
    const int f = blockIdx.x, e = threadIdx.x;
    u_t[(size_t)f * E_DIM + e] = f2bf(u[(size_t)e * E_DIM + f]);
}

// ---------------- Kernel 1: tw[b,e] = sum_t theta[b,t] * w[e,t] ----------------
__global__ __launch_bounds__(E_DIM) void k_thetaw(const float* __restrict__ theta,
                                                  const float* __restrict__ w,
                                                  float* __restrict__ tw,
                                                  int T) {
    __shared__ float th[128];
    const int b = blockIdx.x;
    const int e = threadIdx.x;
    if (threadIdx.x < T) th[threadIdx.x] = theta[b * T + threadIdx.x];
    __syncthreads();
    float acc = 0.f;
    for (int t = 0; t < T; ++t) acc = fmaf(th[t], w[e * T + t], acc);
    tw[b * E_DIM + e] = acc;
}

// ---------------- Kernel 2 (fused): per (b, s-chunk of 32):
//   g_s = sum_f tanh(tw[b,f] + (h@u)[s,f]) * v[f]      (MFMA, bf16)
//   m = max_s g_s;  ex_s = exp(g_s - m);  d = sum ex_s
//   partial[e] = sum_s ex_s * h[s,e]                   (from resident LDS tile)
__global__ __launch_bounds__(256, 4) void k_gate_fused(const float* __restrict__ h,
                                                       const unsigned short* __restrict__ u_t,
                                                       const float* __restrict__ tw_,
                                                       const float* __restrict__ v,
                                                       float* __restrict__ partial,
                                                       float* __restrict__ pm,
                                                       float* __restrict__ pd,
                                                       int S, int SC) {
    __shared__ unsigned short h_lds[GM * E_DIM];  // 16 KB, swizzled
    __shared__ float red[4][GM];                  // 512 B
    __shared__ float exw[GM];                     // 128 B
    __shared__ float pacc[4][E_DIM];              // 4 KB

    const int b   = blockIdx.y;
    const int sc  = blockIdx.x;
    const int tid = threadIdx.x;
    const int w   = tid >> 6;      // wave 0..3
    const int l   = tid & 63;      // lane
    const int lg  = l >> 4;        // k-group 0..3
    const int lc  = l & 15;        // row/col class 0..15
    const int f0w = w * 64;        // wave's f-range base

    // per-lane u base: address for (n,kt) = ubase + n*16*E_DIM + kt*32 (elements)
    const unsigned short* ubase = u_t + (size_t)(f0w + lc) * E_DIM + lg * 8;

    // ---- preload first two k-steps of u (2-deep ring, 32 VGPR) ----
    bf16x8 ua[4], ub2[4];
#pragma unroll
    for (int n = 0; n < 4; ++n)
        ua[n] = *reinterpret_cast<const bf16x8*>(ubase + n * 16 * E_DIM);
#pragma unroll
    for (int n = 0; n < 4; ++n)
        ub2[n] = *reinterpret_cast<const bf16x8*>(ubase + n * 16 * E_DIM + 32);

    // ---- stage h rows sc*32..+31, fp32 -> bf16, coalesced, swizzled LDS ----
    const float* hb = h + ((size_t)b * S + sc * GM) * E_DIM;
    char* ldsb = (char*)h_lds;
#pragma unroll
    for (int it = 0; it < 8; ++it) {
        const int row = it * 4 + w;
        const float4 hv = *reinterpret_cast<const float4*>(hb + (size_t)row * E_DIM + l * 4);
        uint2 pk;
        pk.x = (unsigned)f2bf(hv.x) | ((unsigned)f2bf(hv.y) << 16);
        pk.y = (unsigned)f2bf(hv.z) | ((unsigned)f2bf(hv.w) << 16);
        *reinterpret_cast<uint2*>(ldsb + swz(row * 512 + l * 8)) = pk;
    }

    // ---- per-wave epilogue constants ----
    float tw_f[4], v_f[4];
#pragma unroll
    for (int n = 0; n < 4; ++n) {
        const int f = f0w + n * 16 + lc;
        tw_f[n] = tw_[b * E_DIM + f];
        v_f[n]  = v[f];
    }

    f32x4 acc[2][4];
#pragma unroll
    for (int m = 0; m < 2; ++m)
#pragma unroll
        for (int n = 0; n < 4; ++n)
            acc[m][n] = (f32x4){0.f, 0.f, 0.f, 0.f};

    __syncthreads();   // h_lds ready

    // ---- K loop: 8 k-steps of 32; u ring-prefetched one step ahead.
    //      Loop NOT unrolled (dynamic backedge) so the compiler cannot hoist
    //      all u loads to the top and spill.
    for (int kt4 = 0; kt4 < 4; ++kt4) {
        const int kt0 = kt4 * 2, kt1 = kt4 * 2 + 1;
        // even step: use ua, refill ua with kt0+2
        {
            bf16x8 af0 = *reinterpret_cast<const bf16x8*>(
                ldsb + swz((0 * 16 + lc) * 512 + kt0 * 64 + lg * 16));
            bf16x8 af1 = *reinterpret_cast<const bf16x8*>(
                ldsb + swz((1 * 16 + lc) * 512 + kt0 * 64 + lg * 16));
#pragma unroll
            for (int n = 0; n < 4; ++n) {
                acc[0][n] = __builtin_amdgcn_mfma_f32_16x16x32_bf16(af0, ua[n], acc[0][n], 0, 0, 0);
                acc[1][n] = __builtin_amdgcn_mfma_f32_16x16x32_bf16(af1, ua[n], acc[1][n], 0, 0, 0);
            }
            if (kt4 < 3) {
#pragma unroll
                for (int n = 0; n < 4; ++n)
                    ua[n] = *reinterpret_cast<const bf16x8*>(
                        ubase + n * 16 * E_DIM + (kt0 + 2) * 32);
            }
        }
        // odd step: use ub2, refill ub2 with kt1+2
        {
            bf16x8 af0 = *reinterpret_cast<const bf16x8*>(
                ldsb + swz((0 * 16 + lc) * 512 + kt1 * 64 + lg * 16));
            bf16x8 af1 = *reinterpret_cast<const bf16x8*>(
                ldsb + swz((1 * 16 + lc) * 512 + kt1 * 64 + lg * 16));
#pragma unroll
            for (int n = 0; n < 4; ++n) {
                acc[0][n] = __builtin_amdgcn_mfma_f32_16x16x32_bf16(af0, ub2[n], acc[0][n], 0, 0, 0);
                acc[1][n] = __builtin_amdgcn_mfma_f32_16x16x32_bf16(af1, ub2[n], acc[1][n], 0, 0, 0);
            }
            if (kt4 < 3) {
#pragma unroll
                for (int n = 0; n < 4; ++n)
                    ub2[n] = *reinterpret_cast<const bf16x8*>(
                        ubase + n * 16 * E_DIM + (kt1 + 2) * 32);
            }
        }
    }

    // ---- gate epilogue: tanh(z+tw)*v, sum over f (lc-classes then waves) ----
    float part[2][4] = {};   // [m][i]; row = m*16 + lg*4 + i, col-class lc
#pragma unroll
    for (int n = 0; n < 4; ++n)
#pragma unroll
        for (int m = 0; m < 2; ++m)
#pragma unroll
            for (int i = 0; i < 4; ++i)
                part[m][i] += fast_tanh(acc[m][n][i] + tw_f[n]) * v_f[n];

#pragma unroll
    for (int off = 1; off < 16; off <<= 1)
#pragma unroll
        for (int m = 0; m < 2; ++m)
#pragma unroll
            for (int i = 0; i < 4; ++i)
                part[m][i] += __shfl_xor(part[m][i], off, 64);

    if (lc == 0) {
#pragma unroll
        for (int m = 0; m < 2; ++m)
#pragma unroll
            for (int i = 0; i < 4; ++i)
                red[w][m * 16 + lg * 4 + i] = part[m][i];
    }
    __syncthreads();

    // ---- block softmax stats: lanes 0..31 of wave 0 own the 32 g values ----
    if (tid < GM) {
        const float g = red[0][tid] + red[1][tid] + red[2][tid] + red[3][tid];
        float mx = g;
#pragma unroll
        for (int off = 1; off < 32; off <<= 1)
            mx = fmaxf(mx, __shfl_xor(mx, off, 64));
        const float ex = __expf(g - mx);
        float d = ex;
#pragma unroll
        for (int off = 1; off < 32; off <<= 1)
            d += __shfl_xor(d, off, 64);
        exw[tid] = ex;
        if (tid == 0) {
            pm[(size_t)b * SC + sc] = mx;
            pd[(size_t)b * SC + sc] = d;
        }
    }
    __syncthreads();

    // ---- weighted partial: wave w sums rows w*8..w*8+7; lane owns 4 e-cols ----
    f32x4 a4 = (f32x4){0.f, 0.f, 0.f, 0.f};
#pragma unroll
    for (int j = 0; j < 8; ++j) {
        const int row = w * 8 + j;
        const float ws = exw[row];
        const uint2 hv = *reinterpret_cast<const uint2*>(ldsb + swz(row * 512 + l * 8));
        a4[0] = fmaf(ws, bf2f((unsigned short)(hv.x & 0xffff)), a4[0]);
        a4[1] = fmaf(ws, bf2f((unsigned short)(hv.x >> 16)),    a4[1]);
        a4[2] = fmaf(ws, bf2f((unsigned short)(hv.y & 0xffff)), a4[2]);
        a4[3] = fmaf(ws, bf2f((unsigned short)(hv.y >> 16)),    a4[3]);
    }
    *reinterpret_cast<f32x4*>(&pacc[w][l * 4]) = a4;
    __syncthreads();

    const float p = pacc[0][tid] + pacc[1][tid] + pacc[2][tid] + pacc[3][tid];
    partial[((size_t)b * SC + sc) * E_DIM + tid] = p;
}

// ---------------- Kernel 3: exact softmax merge across chunks ----------------
__global__ __launch_bounds__(256) void k_combine(const float* __restrict__ partial,
                                                 const float* __restrict__ pm,
                                                 const float* __restrict__ pd,
                                                 float* __restrict__ out,
                                                 int SC) {
    const int b = blockIdx.x, t = threadIdx.x;
    __shared__ float sm[128], sd[128];
    if (t < SC) {
        sm[t] = pm[(size_t)b * SC + t];
        sd[t] = pd[(size_t)b * SC + t];
    }
    __syncthreads();

    float M = -3.4e38f;
    for (int c = 0; c < SC; ++c) M = fmaxf(M, sm[c]);

    float num = 0.f, den = 0.f;
    for (int c = 0; c < SC; ++c) {
        const float s = __expf(sm[c] - M);
        den = fmaf(s, sd[c], den);
        num = fmaf(s, partial[((size_t)b * SC + c) * E_DIM + t], num);
    }
    out[(size_t)b * E_DIM + t] = num / den;
}

extern "C" void kernel_launch(void* const* d_in, const int* in_sizes, int n_in,
                              void* d_out, int out_size, void* d_ws, size_t ws_size,
                              hipStream_t stream) {
    const float* h     = (const float*)d_in[0];
    const float* theta = (const float*)d_in[1];
    const float* w     = (const float*)d_in[2];
    const float* v     = (const float*)d_in[3];
    const float* u     = (const float*)d_in[4];
    float* out = (float*)d_out;

    const int E = in_sizes[3];              // 256
    const int T = in_sizes[2] / E;          // 100
    const int B = in_sizes[1] / T;          // 64
    const int S = in_sizes[0] / (B * E);    // 2048
    const int SC = S / GM;                  // 64

    float* tw = (float*)d_ws;                                     // [B,E]
    unsigned short* u_t = (unsigned short*)(tw + (size_t)B * E);  // [E,E] bf16
    float* partial = (float*)(u_t + (size_t)E * E);               // [B,SC,E]
    float* pm = partial + (size_t)B * SC * E;                     // [B,SC]
    float* pd = pm + (size_t)B * SC;                              // [B,SC]

    k_transpose<<<dim3(E), dim3(E), 0, stream>>>(u, u_t);
    k_thetaw<<<dim3(B), dim3(E), 0, stream>>>(theta, w, tw, T);
    k_gate_fused<<<dim3(SC, B), dim3(256), 0, stream>>>(h, u_t, tw, v, partial, pm, pd, S, SC);
    k_combine<<<dim3(B), dim3(256), 0, stream>>>(partial, pm, pd, out, SC);
}